// Round 3
// baseline (152.356 us; speedup 1.0000x reference)
//
#include <hip/hip_runtime.h>
#include <cstdint>
#include <cstddef>

#define BSZ 16
#define LQ  512
#define HIDDIM 768
#define NH  12
#define HD  64
#define R2V 16
#define NTOT 1536   // fused N: K cols [0,768) | V cols [768,1536)
#define MTOT 8192   // BSZ*LQ

typedef __bf16 bf16x8 __attribute__((ext_vector_type(8)));
typedef float  f32x4  __attribute__((ext_vector_type(4)));

__device__ inline unsigned short f2bf(float x) {
    union { float f; unsigned u; } c; c.f = x;
    unsigned r = c.u + 0x7fffu + ((c.u >> 16) & 1u);   // RNE (no NaN here)
    return (unsigned short)(r >> 16);
}
__device__ inline float bfl(unsigned u) { return __uint_as_float(u << 16); }
__device__ inline float bfh(unsigned u) { return __uint_as_float(u & 0xffff0000u); }

// ---------------------------------------------------------------------------
// Kernel 0: cast hs + pack weights (K rows then V rows) to bf16; pack bias.
// ---------------------------------------------------------------------------
#define NHS4 1572864   // 16*512*768/4
#define NW1  147456    // 768*768/4
#define NW4  294912    // 2*768*768/4

__global__ __launch_bounds__(256) void cast_pack(
    const float* __restrict__ hs,
    const float* __restrict__ Kw, const float* __restrict__ Vw,
    const float* __restrict__ Kb, const float* __restrict__ Vb,
    unsigned short* __restrict__ hsb, unsigned short* __restrict__ Wb,
    float* __restrict__ biasp)
{
    const int i = blockIdx.x * 256 + threadIdx.x;
    float4 v; unsigned short* dst;
    if (i < NHS4) {
        v = ((const float4*)hs)[i];
        dst = hsb + (size_t)i * 4;
    } else {
        const int j = i - NHS4;
        v = (j < NW1) ? ((const float4*)Kw)[j] : ((const float4*)Vw)[j - NW1];
        dst = Wb + (size_t)j * 4;
    }
    ushort4 o;
    o.x = f2bf(v.x); o.y = f2bf(v.y); o.z = f2bf(v.z); o.w = f2bf(v.w);
    *(ushort4*)dst = o;
    if (i < 768) { biasp[i] = Kb[i]; biasp[768 + i] = Vb[i]; }
}

// ---------------------------------------------------------------------------
// Kernel 1: bf16 MFMA GEMM -> bf16 outputs.  256x256 tile, BK=32, 512 thr =
// 8 waves (2Mx4N bands, per-wave 128x64 output), 16x16x32 MFMA, acc[8][4].
// STATIC 64 KB LDS, double-buffered (2 x 16 KB per matrix); one barrier per
// K-tile: the barrier at iter t drains the global_load_lds issued at t-1.
// 32 MFMA/wave per barrier (2x the 128^2 structure) and 2x the arithmetic
// intensity per staged byte.
// T2-style involution swizzle on 16B units within each 64B row:
//   s(row) = (row>>1)&3; LDS[row][u] holds global col ((u^s)*8).
// Write side: linear gld_lds dest (wave-uniform base) + pre-swizzled global
// source column; read side: unit = fj ^ s(row).  Swizzle term is invariant
// to all row-base offsets (multiples of 16), so it cancels exactly.
// Swapped-operand MFMA -> C^T layout -> ushort4 stores; identical k-order
// accumulation to the verified 128^2 kernel -> bit-identical output.
// ---------------------------------------------------------------------------
#define TBM 256
#define TBN 256
#define TBK 32
#define KT  (HIDDIM / TBK)    // 24
#define ATILE (TBM * TBK)     // 8192 elements = 16 KB

#define GLD16(g, l) __builtin_amdgcn_global_load_lds( \
    (const __attribute__((address_space(1))) void*)(g), \
    (__attribute__((address_space(3))) void*)(l), 16, 0, 0)

__global__ __launch_bounds__(512, 2) void gemm_mfma(
    const unsigned short* __restrict__ Abf,   // 8192 x 768 bf16
    const unsigned short* __restrict__ Wbf,   // 1536 x 768 bf16
    const float* __restrict__ biasp,          // 1536 fp32
    unsigned short* __restrict__ K1b, unsigned short* __restrict__ V1b)
{
    __shared__ unsigned short As[2][ATILE];   // 32 KB
    __shared__ unsigned short Bs[2][ATILE];   // 32 KB

    const int n0   = blockIdx.x * TBN;
    const int m0   = blockIdx.y * TBM;
    const int tid  = threadIdx.x;
    const int wid  = tid >> 6;
    const int lane = tid & 63;
    const int wr   = wid >> 2;      // 0..1 : 128-row (M) band
    const int wc   = wid & 3;       // 0..3 : 64-col (N) band

    f32x4 acc[8][4] = {};

    // ---- staging geometry: wave wid stages rows [wid*32, wid*32+32) of
    // both A and B per K-tile, as 2 chunks of 16 rows (1 KB each).
    // lane -> row = lane>>2, unit = lane&3.  Source column pre-swizzled:
    // unit ^= (row>>1)&3 == (lane>>3)&3  (row-base offsets don't affect s).
    const int srow = lane >> 2;                               // 0..15
    const int scol = ((lane & 3) ^ ((lane >> 3) & 3)) << 3;   // elements
    const int r0   = wid * 32;

    const unsigned short* Ag = Abf + (size_t)(m0 + r0 + srow) * HIDDIM + scol;
    const unsigned short* Bg = Wbf + (size_t)(n0 + r0 + srow) * HIDDIM + scol;

#define STAGE(buf, kt) do {                                                   \
        const int kof_ = (kt) * TBK;                                          \
        GLD16(Ag + kof_,                    &As[buf][r0 * TBK]);              \
        GLD16(Ag + 16 * HIDDIM + kof_,      &As[buf][(r0 + 16) * TBK]);       \
        GLD16(Bg + kof_,                    &Bs[buf][r0 * TBK]);              \
        GLD16(Bg + 16 * HIDDIM + kof_,      &Bs[buf][(r0 + 16) * TBK]);       \
    } while (0)

    // ---- fragment read geometry (swizzled) ----
    const int fm   = lane & 15;                         // M/N index in frag
    const int fj   = lane >> 4;                         // 0..3 : k-subgroup
    const int koff = ((fj ^ ((fm >> 1) & 3)) << 3);     // swizzled elem off

    STAGE(0, 0);   // prologue: stage tile 0 into buf 0

    for (int kt = 0; kt < KT; ++kt) {
        __syncthreads();   // drains STAGE(kt) [vmcnt] + protects LDS reuse
        if (kt + 1 < KT) STAGE((kt + 1) & 1, kt + 1);
        const int cb = kt & 1;

        bf16x8 af[8], bfr[4];
        #pragma unroll
        for (int mi = 0; mi < 8; ++mi)
            af[mi] = *reinterpret_cast<const bf16x8*>(
                &As[cb][(wr * 128 + mi * 16 + fm) * TBK + koff]);
        #pragma unroll
        for (int ni = 0; ni < 4; ++ni)
            bfr[ni] = *reinterpret_cast<const bf16x8*>(
                &Bs[cb][(wc * 64 + ni * 16 + fm) * TBK + koff]);
        __builtin_amdgcn_s_setprio(1);
        #pragma unroll
        for (int mi = 0; mi < 8; ++mi)
            #pragma unroll
            for (int ni = 0; ni < 4; ++ni)
                acc[mi][ni] = __builtin_amdgcn_mfma_f32_16x16x32_bf16(
                    bfr[ni], af[mi], acc[mi][ni], 0, 0, 0);   // swapped: C^T
        __builtin_amdgcn_s_setprio(0);
    }
#undef STAGE

    // epilogue: lane holds m = fm, n = fj*4 + r (4 consecutive)
    const bool isK = (n0 < HIDDIM);
    unsigned short* __restrict__ dst = isK ? K1b : V1b;
    const int nsub = isK ? 0 : HIDDIM;
    const int nq   = fj * 4;

    #pragma unroll
    for (int ni = 0; ni < 4; ++ni) {
        const int ng = n0 + wc * 64 + ni * 16 + nq;
        const float4 bv = *(const float4*)(biasp + ng);
        #pragma unroll
        for (int mi = 0; mi < 8; ++mi) {
            const int mg = m0 + wr * 128 + mi * 16 + fm;
            f32x4 a = acc[mi][ni];
            ushort4 o;
            o.x = f2bf(fmaxf(a[0] + bv.x, 0.f));
            o.y = f2bf(fmaxf(a[1] + bv.y, 0.f));
            o.z = f2bf(fmaxf(a[2] + bv.z, 0.f));
            o.w = f2bf(fmaxf(a[3] + bv.w, 0.f));
            *(ushort4*)(dst + (size_t)mg * HIDDIM + (ng - nsub)) = o;
        }
    }
}

// ---------------------------------------------------------------------------
// Kernel 2: fused per (b,h): scores -> softmax(+exp(-m)) -> events -> scans
// -> idx (LDS) -> gather from V1b -> out.  512 threads = 8 waves.
// 4 blocks per (b,h): all run the cheap score/scan phases redundantly,
// each gathers 2 of 8 rounds (occupancy for the L2-latency-bound gather).
// ---------------------------------------------------------------------------
#define SINF (1 << 30)
#define IXP 17   // idxs row stride (pad 16->17)

__global__ __launch_bounds__(512) void scan_gather(
    const unsigned short* __restrict__ K1b,
    const unsigned short* __restrict__ V1b,
    const float* __restrict__ rh,
    const float* __restrict__ bw,
    float* __restrict__ out)
{
    const int bh   = blockIdx.x >> 2;  // 0..191
    const int part = blockIdx.x & 3;   // which pair of gather rounds
    const int b    = bh / NH;
    const int h    = bh % NH;
    const int l    = threadIdx.x;      // 0..511
    const int lane = l & 63;
    const int wid  = l >> 6;

    __shared__ float wredA[8];
    __shared__ float wredB[8];
    __shared__ int   wp0[8];
    __shared__ int   wp1[8];
    __shared__ int   wp2[8];
    __shared__ int   ev[LQ];
    __shared__ int   col0[LQ];
    __shared__ int   col1[LQ];
    __shared__ int   E[LQ];
    __shared__ int   idxs[LQ * IXP];   // ~34.8 KB
    __shared__ float wsm[R2V];

    if (l < R2V) wsm[l] = bw[h * R2V + l];

    // ---- 1. score: dot64(bf16 K1 row, fp32 reading_head) ----
    const unsigned short* krow = K1b + ((size_t)(b * LQ + l)) * HIDDIM + h * HD;
    const float* rrow = rh + h * HD;
    float s = 0.f;
    #pragma unroll
    for (int c8 = 0; c8 < 8; ++c8) {
        uint4 kv = *(const uint4*)(krow + c8 * 8);
        float4 ra = *(const float4*)(rrow + c8 * 8);
        float4 rb = *(const float4*)(rrow + c8 * 8 + 4);
        s += bfl(kv.x) * ra.x + bfh(kv.x) * ra.y
           + bfl(kv.y) * ra.z + bfh(kv.y) * ra.w
           + bfl(kv.z) * rb.x + bfh(kv.z) * rb.y
           + bfl(kv.w) * rb.z + bfh(kv.w) * rb.w;
    }

    // ---- 2. max reduce ----
    float mx = s;
    #pragma unroll
    for (int off = 32; off > 0; off >>= 1) mx = fmaxf(mx, __shfl_xor(mx, off));
    if (lane == 0) wredA[wid] = mx;
    __syncthreads();
    float m = wredA[0];
    #pragma unroll
    for (int i = 1; i < 8; ++i) m = fmaxf(m, wredA[i]);

    // ---- 3. sum reduce ----
    const float e = expf(s - m);
    float sm = e;
    #pragma unroll
    for (int off = 32; off > 0; off >>= 1) sm += __shfl_xor(sm, off);
    if (lane == 0) wredB[wid] = sm;
    __syncthreads();
    float ssum = 0.f;
    #pragma unroll
    for (int i = 0; i < 8; ++i) ssum += wredB[i];

    const float p = e / ssum + expf(-m);
    const int event = (p > (1.5f / 512.0f)) ? 1 : 0;
    ev[l] = event;

    // ---- 4. col0: inclusive max-scan of (event ? l : -1) ----
    int v = event ? l : -1;
    #pragma unroll
    for (int off = 1; off < 64; off <<= 1) {
        int u = __shfl_up(v, off);
        if (lane >= off) v = (u > v) ? u : v;
    }
    if (lane == 63) wp0[wid] = v;
    __syncthreads();                     // ev + wp0 visible
    int pfx = -1;
    for (int i = 0; i < wid; ++i) pfx = (wp0[i] > pfx) ? wp0[i] : pfx;
    v = (pfx > v) ? pfx : v;
    col0[l] = (v >= 0) ? v : l;

    // ---- 5. col1: suffix min-scan of (ev[(l+1)&511] ? l : INF) ----
    int v1 = ev[(l + 1) & (LQ - 1)] ? l : SINF;
    #pragma unroll
    for (int off = 1; off < 64; off <<= 1) {
        int u = __shfl_down(v1, off);
        if (lane < 64 - off) v1 = (u < v1) ? u : v1;
    }
    if (lane == 0) wp1[wid] = v1;
    __syncthreads();
    int sfx = SINF;
    for (int i = wid + 1; i < 8; ++i) sfx = (wp1[i] < sfx) ? wp1[i] : sfx;
    v1 = (sfx < v1) ? sfx : v1;
    col1[l] = (l == 0) ? 0 : (((v1 < SINF) ? v1 : l) + 1);

    // ---- 6. prefix count of events over steps 1..l ----
    int c = (l >= 1) ? event : 0;
    #pragma unroll
    for (int off = 1; off < 64; off <<= 1) {
        int u = __shfl_up(c, off);
        if (lane >= off) c += u;
    }
    if (lane == 63) wp2[wid] = c;
    __syncthreads();
    for (int i = 0; i < wid; ++i) c += wp2[i];

    // ---- 7. event-time list ----
    if (l >= 1 && event) E[c - 1] = l;
    __syncthreads();                     // E, col0, col1 ready

    // ---- 8. idx registers -> LDS ----
    int* op = &idxs[l * IXP];
    #pragma unroll
    for (int j = 0; j < 8; ++j) {
        const int k = c - 1 - j;
        int f = 0, bb = 0;
        if (k >= 0) {
            const int t = E[k];          // t >= 1
            f  = col0[t - 1];
            bb = col1[t - 1];
        }
        op[2 * j]     = min(max(f, 0), LQ - 1);
        op[2 * j + 1] = min(max(bb, 0), LQ - 1);
    }
    __syncthreads();                     // idxs + wsm ready

    // ---- 9. gather: 8 lanes per l (dsl covers 8 d's), this block's 2 of 8
    //         rounds, 4-chunked ----
    const int dsl = lane & 7;
    const size_t vbase = (size_t)b * LQ * HIDDIM + h * HD + dsl * 8;

    for (int rr = 0; rr < 2; ++rr) {
        const int round = part * 2 + rr;
        const int lg = round * 64 + wid * 8 + (lane >> 3);
        const int* ip = &idxs[lg * IXP];
        float a0 = 0.f, a1 = 0.f, a2 = 0.f, a3 = 0.f;
        float a4 = 0.f, a5 = 0.f, a6 = 0.f, a7 = 0.f;
        #pragma unroll 1
        for (int rc = 0; rc < R2V; rc += 4) {
            const int i0 = ip[rc], i1 = ip[rc + 1], i2 = ip[rc + 2], i3 = ip[rc + 3];
            uint4 v0 = *(const uint4*)(V1b + vbase + (size_t)i0 * HIDDIM);
            uint4 vA = *(const uint4*)(V1b + vbase + (size_t)i1 * HIDDIM);
            uint4 vB = *(const uint4*)(V1b + vbase + (size_t)i2 * HIDDIM);
            uint4 vC = *(const uint4*)(V1b + vbase + (size_t)i3 * HIDDIM);
            const float w0 = wsm[rc], w1 = wsm[rc + 1], w2 = wsm[rc + 2], w3 = wsm[rc + 3];
            a0 += w0 * bfl(v0.x); a1 += w0 * bfh(v0.x);
            a2 += w0 * bfl(v0.y); a3 += w0 * bfh(v0.y);
            a4 += w0 * bfl(v0.z); a5 += w0 * bfh(v0.z);
            a6 += w0 * bfl(v0.w); a7 += w0 * bfh(v0.w);
            a0 += w1 * bfl(vA.x); a1 += w1 * bfh(vA.x);
            a2 += w1 * bfl(vA.y); a3 += w1 * bfh(vA.y);
            a4 += w1 * bfl(vA.z); a5 += w1 * bfh(vA.z);
            a6 += w1 * bfl(vA.w); a7 += w1 * bfh(vA.w);
            a0 += w2 * bfl(vB.x); a1 += w2 * bfh(vB.x);
            a2 += w2 * bfl(vB.y); a3 += w2 * bfh(vB.y);
            a4 += w2 * bfl(vB.z); a5 += w2 * bfh(vB.z);
            a6 += w2 * bfl(vB.w); a7 += w2 * bfh(vB.w);
            a0 += w3 * bfl(vC.x); a1 += w3 * bfh(vC.x);
            a2 += w3 * bfl(vC.y); a3 += w3 * bfh(vC.y);
            a4 += w3 * bfl(vC.z); a5 += w3 * bfh(vC.z);
            a6 += w3 * bfl(vC.w); a7 += w3 * bfh(vC.w);
        }
        float* po = out + ((size_t)(b * LQ + lg) * NH + h) * HD + dsl * 8;
        *(float4*)po       = make_float4(a0, a1, a2, a3);
        *((float4*)po + 1) = make_float4(a4, a5, a6, a7);
    }
}

// ---------------------------------------------------------------------------
extern "C" void kernel_launch(void* const* d_in, const int* in_sizes, int n_in,
                              void* d_out, int out_size, void* d_ws, size_t ws_size,
                              hipStream_t stream)
{
    (void)in_sizes; (void)n_in; (void)out_size; (void)ws_size;

    const float* hs = (const float*)d_in[0];
    const float* Kw = (const float*)d_in[1];
    const float* Kb = (const float*)d_in[2];
    const float* Vw = (const float*)d_in[3];
    const float* Vb = (const float*)d_in[4];
    const float* rh = (const float*)d_in[5];
    const float* bw = (const float*)d_in[6];
    float* out = (float*)d_out;

    // ws layout (bytes):
    //   K1b  bf16 8192*768  @ 0         (12.58 MB)
    //   V1b  bf16 8192*768  @ 12582912  (12.58 MB)
    //   hsb  bf16 8192*768  @ 25165824  (12.58 MB)
    //   Wb   bf16 1536*768  @ 37748736  ( 2.36 MB)
    //   bias fp32 1536      @ 40108032  ( 6 KB)
    char* ws = (char*)d_ws;
    unsigned short* K1b   = (unsigned short*)(ws);
    unsigned short* V1b   = (unsigned short*)(ws + 12582912);
    unsigned short* hsb   = (unsigned short*)(ws + 25165824);
    unsigned short* Wb    = (unsigned short*)(ws + 37748736);
    float*          biasp = (float*)(ws + 40108032);

    cast_pack<<<(NHS4 + NW4) / 256, 256, 0, stream>>>(hs, Kw, Vw, Kb, Vb, hsb, Wb, biasp);

    dim3 g1(NTOT / TBN, MTOT / TBM);   // 6 x 32 = 192 blocks (1 per CU, 8 waves)
    gemm_mfma<<<g1, 512, 0, stream>>>(hsb, Wb, biasp, K1b, V1b);

    scan_gather<<<BSZ * NH * 4, LQ, 0, stream>>>(K1b, V1b, rh, bw, out);
}

// Round 4
// 140.710 us; speedup vs baseline: 1.0828x; 1.0828x over previous
//
#include <hip/hip_runtime.h>
#include <cstdint>
#include <cstddef>

#define BSZ 16
#define LQ  512
#define HIDDIM 768
#define NH  12
#define HD  64
#define R2V 16
#define NTOT 1536   // fused N: K cols [0,768) | V cols [768,1536)
#define MTOT 8192   // BSZ*LQ

typedef __bf16 bf16x8 __attribute__((ext_vector_type(8)));
typedef float  f32x4  __attribute__((ext_vector_type(4)));

__device__ inline unsigned short f2bf(float x) {
    union { float f; unsigned u; } c; c.f = x;
    unsigned r = c.u + 0x7fffu + ((c.u >> 16) & 1u);   // RNE (no NaN here)
    return (unsigned short)(r >> 16);
}
__device__ inline float bfl(unsigned u) { return __uint_as_float(u << 16); }
__device__ inline float bfh(unsigned u) { return __uint_as_float(u & 0xffff0000u); }

// ---------------------------------------------------------------------------
// Kernel 0: cast hs + pack weights (K rows then V rows) to bf16; pack bias.
// ---------------------------------------------------------------------------
#define NHS4 1572864   // 16*512*768/4
#define NW1  147456    // 768*768/4
#define NW4  294912    // 2*768*768/4

__global__ __launch_bounds__(256) void cast_pack(
    const float* __restrict__ hs,
    const float* __restrict__ Kw, const float* __restrict__ Vw,
    const float* __restrict__ Kb, const float* __restrict__ Vb,
    unsigned short* __restrict__ hsb, unsigned short* __restrict__ Wb,
    float* __restrict__ biasp)
{
    const int i = blockIdx.x * 256 + threadIdx.x;
    float4 v; unsigned short* dst;
    if (i < NHS4) {
        v = ((const float4*)hs)[i];
        dst = hsb + (size_t)i * 4;
    } else {
        const int j = i - NHS4;
        v = (j < NW1) ? ((const float4*)Kw)[j] : ((const float4*)Vw)[j - NW1];
        dst = Wb + (size_t)j * 4;
    }
    ushort4 o;
    o.x = f2bf(v.x); o.y = f2bf(v.y); o.z = f2bf(v.z); o.w = f2bf(v.w);
    *(ushort4*)dst = o;
    if (i < 768) { biasp[i] = Kb[i]; biasp[768 + i] = Vb[i]; }
}

// ---------------------------------------------------------------------------
// Kernel 1: bf16 MFMA GEMM -> bf16 outputs.  128x128 tile, BK=32, 256 thr =
// 4 waves, 16x16x32 MFMA, acc[4][4] per wave.
// COUNTED-VMCNT PIPELINE (T3+T4): TRIPLE-buffered LDS (48 KB -> 3 blocks/CU,
// 3 waves/SIMD).  Tile t's loads are issued at iter t-2 (2 iters of flight
// ~= HBM latency).  Main-loop wait is s_waitcnt vmcnt(4) — drains tile t's
// 4 loads/thread, keeps tile t+1's 4 in flight ACROSS the raw s_barrier
// (never vmcnt(0) until the last iter).  STAGE is issued after the barrier
// (all waves have finished reading the buffer being overwritten).
// Soundness: every wave issues the same 4-load cadence per iter, so after
// each wave's own vmcnt(4)+barrier, ALL waves' tile-t loads are complete.
// T2 involution swizzle on 16B units within each 64B row (verified R3,
// conflicts=0): s(row)=(row>>1)&3; write side pre-swizzles the GLOBAL
// source column (linear gld_lds dest); read side XORs the same term.
// T1 XCD remap: 768 blocks, each XCD gets 96 consecutive (by,bx) ->
// concurrent per-XCD working set ~= 8 A-panels + all B ~= 4 MB ~= L2.
// Swapped-operand MFMA -> C^T layout; identical k-order accumulation to the
// verified kernels -> bit-identical output.
// ---------------------------------------------------------------------------
#define TBM 128
#define TBN 128
#define TBK 32
#define KT  (HIDDIM / TBK)    // 24
#define ATILE (TBM * TBK)     // 4096 elements = 8 KB

#define GLD16(g, l) __builtin_amdgcn_global_load_lds( \
    (const __attribute__((address_space(1))) void*)(g), \
    (__attribute__((address_space(3))) void*)(l), 16, 0, 0)

__global__ __launch_bounds__(256, 3) void gemm_mfma(
    const unsigned short* __restrict__ Abf,   // 8192 x 768 bf16
    const unsigned short* __restrict__ Wbf,   // 1536 x 768 bf16
    const float* __restrict__ biasp,          // 1536 fp32
    unsigned short* __restrict__ K1b, unsigned short* __restrict__ V1b)
{
    __shared__ unsigned short As[3][ATILE];   // 24 KB
    __shared__ unsigned short Bs[3][ATILE];   // 24 KB

    // ---- T1: XCD-aware bijective remap (768 % 8 == 0) ----
    const int wg  = blockIdx.y * 12 + blockIdx.x;     // gridDim = (12, 64)
    const int nid = (wg & 7) * 96 + (wg >> 3);
    const int bx  = nid % 12;
    const int by  = nid / 12;
    const int n0  = bx * TBN;
    const int m0  = by * TBM;

    const int tid  = threadIdx.x;
    const int wid  = tid >> 6;
    const int lane = tid & 63;
    const int wm   = (wid & 1) * 64;
    const int wn   = (wid >> 1) * 64;

    f32x4 acc[4][4] = {};   // lane holds m=lane&15, n-quad=(lane>>4)*4 (C^T)

    // ---- staging: wave wid stages rows [wid*32, wid*32+32) of A and B,
    // 2 chunks of 16 rows each.  lane -> row = lane>>2, unit = lane&3.
    // Source column pre-swizzled: unit ^= s(row) = (row>>1)&3 = (lane>>3)&3
    // (all row-base offsets are multiples of 16 -> s unaffected).
    const int srow = lane >> 2;                               // 0..15
    const int scol = ((lane & 3) ^ ((lane >> 3) & 3)) << 3;   // elements
    const int r0   = wid * 32;

    const unsigned short* Ag = Abf + (size_t)(m0 + r0 + srow) * HIDDIM + scol;
    const unsigned short* Bg = Wbf + (size_t)(n0 + r0 + srow) * HIDDIM + scol;

#define STAGE(buf, kt) do {                                                   \
        const int kof_ = (kt) * TBK;                                          \
        GLD16(Ag + kof_,               &As[buf][r0 * TBK]);                   \
        GLD16(Ag + 16 * HIDDIM + kof_, &As[buf][(r0 + 16) * TBK]);            \
        GLD16(Bg + kof_,               &Bs[buf][r0 * TBK]);                   \
        GLD16(Bg + 16 * HIDDIM + kof_, &Bs[buf][(r0 + 16) * TBK]);            \
    } while (0)

    // ---- fragment read geometry (swizzled) ----
    const int fm   = lane & 15;                         // M/N index in frag
    const int fj   = lane >> 4;                         // 0..3 : k-subgroup
    const int koff = ((fj ^ ((fm >> 1) & 3)) << 3);     // swizzled elem off

    STAGE(0, 0);   // prologue: tiles 0 and 1 in flight
    STAGE(1, 1);

    for (int kt = 0; kt < KT; ++kt) {
        // drain tile kt's 4 loads/thread; keep tile kt+1's 4 in flight
        if (kt < KT - 1) asm volatile("s_waitcnt vmcnt(4)" ::: "memory");
        else             asm volatile("s_waitcnt vmcnt(0)" ::: "memory");
        __builtin_amdgcn_s_barrier();
        __builtin_amdgcn_sched_barrier(0);
        if (kt + 2 < KT) STAGE((kt + 2) % 3, kt + 2);
        const int cb = kt % 3;

        bf16x8 af[4], bfr[4];
        #pragma unroll
        for (int mi = 0; mi < 4; ++mi)
            af[mi] = *reinterpret_cast<const bf16x8*>(
                &As[cb][(wm + mi * 16 + fm) * TBK + koff]);
        #pragma unroll
        for (int ni = 0; ni < 4; ++ni)
            bfr[ni] = *reinterpret_cast<const bf16x8*>(
                &Bs[cb][(wn + ni * 16 + fm) * TBK + koff]);
        __builtin_amdgcn_s_setprio(1);
        #pragma unroll
        for (int mi = 0; mi < 4; ++mi)
            #pragma unroll
            for (int ni = 0; ni < 4; ++ni)
                acc[mi][ni] = __builtin_amdgcn_mfma_f32_16x16x32_bf16(
                    bfr[ni], af[mi], acc[mi][ni], 0, 0, 0);   // swapped: C^T
        __builtin_amdgcn_s_setprio(0);
    }
#undef STAGE

    // epilogue: lane holds m = fm, n = fj*4 + r (4 consecutive)
    const bool isK = (n0 < HIDDIM);
    unsigned short* __restrict__ dst = isK ? K1b : V1b;
    const int nsub = isK ? 0 : HIDDIM;
    const int nq   = fj * 4;

    #pragma unroll
    for (int mi = 0; mi < 4; ++mi) {
        const int mg = m0 + wm + mi * 16 + fm;
        #pragma unroll
        for (int ni = 0; ni < 4; ++ni) {
            const int ng = n0 + wn + ni * 16 + nq;
            float4 bv = *(const float4*)(biasp + ng);
            f32x4 a = acc[mi][ni];
            ushort4 o;
            o.x = f2bf(fmaxf(a[0] + bv.x, 0.f));
            o.y = f2bf(fmaxf(a[1] + bv.y, 0.f));
            o.z = f2bf(fmaxf(a[2] + bv.z, 0.f));
            o.w = f2bf(fmaxf(a[3] + bv.w, 0.f));
            *(ushort4*)(dst + (size_t)mg * HIDDIM + (ng - nsub)) = o;
        }
    }
}

// ---------------------------------------------------------------------------
// Kernel 2: fused per (b,h): scores -> softmax(+exp(-m)) -> events -> scans
// -> idx (LDS) -> gather from V1b -> out.  512 threads = 8 waves.
// 4 blocks per (b,h): all run the cheap score/scan phases redundantly,
// each gathers 2 of 8 rounds (occupancy for the L2-latency-bound gather).
// ---------------------------------------------------------------------------
#define SINF (1 << 30)
#define IXP 17   // idxs row stride (pad 16->17)

__global__ __launch_bounds__(512) void scan_gather(
    const unsigned short* __restrict__ K1b,
    const unsigned short* __restrict__ V1b,
    const float* __restrict__ rh,
    const float* __restrict__ bw,
    float* __restrict__ out)
{
    const int bh   = blockIdx.x >> 2;  // 0..191
    const int part = blockIdx.x & 3;   // which pair of gather rounds
    const int b    = bh / NH;
    const int h    = bh % NH;
    const int l    = threadIdx.x;      // 0..511
    const int lane = l & 63;
    const int wid  = l >> 6;

    __shared__ float wredA[8];
    __shared__ float wredB[8];
    __shared__ int   wp0[8];
    __shared__ int   wp1[8];
    __shared__ int   wp2[8];
    __shared__ int   ev[LQ];
    __shared__ int   col0[LQ];
    __shared__ int   col1[LQ];
    __shared__ int   E[LQ];
    __shared__ int   idxs[LQ * IXP];   // ~34.8 KB
    __shared__ float wsm[R2V];

    if (l < R2V) wsm[l] = bw[h * R2V + l];

    // ---- 1. score: dot64(bf16 K1 row, fp32 reading_head) ----
    const unsigned short* krow = K1b + ((size_t)(b * LQ + l)) * HIDDIM + h * HD;
    const float* rrow = rh + h * HD;
    float s = 0.f;
    #pragma unroll
    for (int c8 = 0; c8 < 8; ++c8) {
        uint4 kv = *(const uint4*)(krow + c8 * 8);
        float4 ra = *(const float4*)(rrow + c8 * 8);
        float4 rb = *(const float4*)(rrow + c8 * 8 + 4);
        s += bfl(kv.x) * ra.x + bfh(kv.x) * ra.y
           + bfl(kv.y) * ra.z + bfh(kv.y) * ra.w
           + bfl(kv.z) * rb.x + bfh(kv.z) * rb.y
           + bfl(kv.w) * rb.z + bfh(kv.w) * rb.w;
    }

    // ---- 2. max reduce ----
    float mx = s;
    #pragma unroll
    for (int off = 32; off > 0; off >>= 1) mx = fmaxf(mx, __shfl_xor(mx, off));
    if (lane == 0) wredA[wid] = mx;
    __syncthreads();
    float m = wredA[0];
    #pragma unroll
    for (int i = 1; i < 8; ++i) m = fmaxf(m, wredA[i]);

    // ---- 3. sum reduce ----
    const float e = expf(s - m);
    float sm = e;
    #pragma unroll
    for (int off = 32; off > 0; off >>= 1) sm += __shfl_xor(sm, off);
    if (lane == 0) wredB[wid] = sm;
    __syncthreads();
    float ssum = 0.f;
    #pragma unroll
    for (int i = 0; i < 8; ++i) ssum += wredB[i];

    const float p = e / ssum + expf(-m);
    const int event = (p > (1.5f / 512.0f)) ? 1 : 0;
    ev[l] = event;

    // ---- 4. col0: inclusive max-scan of (event ? l : -1) ----
    int v = event ? l : -1;
    #pragma unroll
    for (int off = 1; off < 64; off <<= 1) {
        int u = __shfl_up(v, off);
        if (lane >= off) v = (u > v) ? u : v;
    }
    if (lane == 63) wp0[wid] = v;
    __syncthreads();                     // ev + wp0 visible
    int pfx = -1;
    for (int i = 0; i < wid; ++i) pfx = (wp0[i] > pfx) ? wp0[i] : pfx;
    v = (pfx > v) ? pfx : v;
    col0[l] = (v >= 0) ? v : l;

    // ---- 5. col1: suffix min-scan of (ev[(l+1)&511] ? l : INF) ----
    int v1 = ev[(l + 1) & (LQ - 1)] ? l : SINF;
    #pragma unroll
    for (int off = 1; off < 64; off <<= 1) {
        int u = __shfl_down(v1, off);
        if (lane < 64 - off) v1 = (u < v1) ? u : v1;
    }
    if (lane == 0) wp1[wid] = v1;
    __syncthreads();
    int sfx = SINF;
    for (int i = wid + 1; i < 8; ++i) sfx = (wp1[i] < sfx) ? wp1[i] : sfx;
    v1 = (sfx < v1) ? sfx : v1;
    col1[l] = (l == 0) ? 0 : (((v1 < SINF) ? v1 : l) + 1);

    // ---- 6. prefix count of events over steps 1..l ----
    int c = (l >= 1) ? event : 0;
    #pragma unroll
    for (int off = 1; off < 64; off <<= 1) {
        int u = __shfl_up(c, off);
        if (lane >= off) c += u;
    }
    if (lane == 63) wp2[wid] = c;
    __syncthreads();
    for (int i = 0; i < wid; ++i) c += wp2[i];

    // ---- 7. event-time list ----
    if (l >= 1 && event) E[c - 1] = l;
    __syncthreads();                     // E, col0, col1 ready

    // ---- 8. idx registers -> LDS ----
    int* op = &idxs[l * IXP];
    #pragma unroll
    for (int j = 0; j < 8; ++j) {
        const int k = c - 1 - j;
        int f = 0, bb = 0;
        if (k >= 0) {
            const int t = E[k];          // t >= 1
            f  = col0[t - 1];
            bb = col1[t - 1];
        }
        op[2 * j]     = min(max(f, 0), LQ - 1);
        op[2 * j + 1] = min(max(bb, 0), LQ - 1);
    }
    __syncthreads();                     // idxs + wsm ready

    // ---- 9. gather: 8 lanes per l (dsl covers 8 d's), this block's 2 of 8
    //         rounds, 4-chunked ----
    const int dsl = lane & 7;
    const size_t vbase = (size_t)b * LQ * HIDDIM + h * HD + dsl * 8;

    for (int rr = 0; rr < 2; ++rr) {
        const int round = part * 2 + rr;
        const int lg = round * 64 + wid * 8 + (lane >> 3);
        const int* ip = &idxs[lg * IXP];
        float a0 = 0.f, a1 = 0.f, a2 = 0.f, a3 = 0.f;
        float a4 = 0.f, a5 = 0.f, a6 = 0.f, a7 = 0.f;
        #pragma unroll 1
        for (int rc = 0; rc < R2V; rc += 4) {
            const int i0 = ip[rc], i1 = ip[rc + 1], i2 = ip[rc + 2], i3 = ip[rc + 3];
            uint4 v0 = *(const uint4*)(V1b + vbase + (size_t)i0 * HIDDIM);
            uint4 vA = *(const uint4*)(V1b + vbase + (size_t)i1 * HIDDIM);
            uint4 vB = *(const uint4*)(V1b + vbase + (size_t)i2 * HIDDIM);
            uint4 vC = *(const uint4*)(V1b + vbase + (size_t)i3 * HIDDIM);
            const float w0 = wsm[rc], w1 = wsm[rc + 1], w2 = wsm[rc + 2], w3 = wsm[rc + 3];
            a0 += w0 * bfl(v0.x); a1 += w0 * bfh(v0.x);
            a2 += w0 * bfl(v0.y); a3 += w0 * bfh(v0.y);
            a4 += w0 * bfl(v0.z); a5 += w0 * bfh(v0.z);
            a6 += w0 * bfl(v0.w); a7 += w0 * bfh(v0.w);
            a0 += w1 * bfl(vA.x); a1 += w1 * bfh(vA.x);
            a2 += w1 * bfl(vA.y); a3 += w1 * bfh(vA.y);
            a4 += w1 * bfl(vA.z); a5 += w1 * bfh(vA.z);
            a6 += w1 * bfl(vA.w); a7 += w1 * bfh(vA.w);
            a0 += w2 * bfl(vB.x); a1 += w2 * bfh(vB.x);
            a2 += w2 * bfl(vB.y); a3 += w2 * bfh(vB.y);
            a4 += w2 * bfl(vB.z); a5 += w2 * bfh(vB.z);
            a6 += w2 * bfl(vB.w); a7 += w2 * bfh(vB.w);
            a0 += w3 * bfl(vC.x); a1 += w3 * bfh(vC.x);
            a2 += w3 * bfl(vC.y); a3 += w3 * bfh(vC.y);
            a4 += w3 * bfl(vC.z); a5 += w3 * bfh(vC.z);
            a6 += w3 * bfl(vC.w); a7 += w3 * bfh(vC.w);
        }
        float* po = out + ((size_t)(b * LQ + lg) * NH + h) * HD + dsl * 8;
        *(float4*)po       = make_float4(a0, a1, a2, a3);
        *((float4*)po + 1) = make_float4(a4, a5, a6, a7);
    }
}

// ---------------------------------------------------------------------------
extern "C" void kernel_launch(void* const* d_in, const int* in_sizes, int n_in,
                              void* d_out, int out_size, void* d_ws, size_t ws_size,
                              hipStream_t stream)
{
    (void)in_sizes; (void)n_in; (void)out_size; (void)ws_size;

    const float* hs = (const float*)d_in[0];
    const float* Kw = (const float*)d_in[1];
    const float* Kb = (const float*)d_in[2];
    const float* Vw = (const float*)d_in[3];
    const float* Vb = (const float*)d_in[4];
    const float* rh = (const float*)d_in[5];
    const float* bw = (const float*)d_in[6];
    float* out = (float*)d_out;

    // ws layout (bytes):
    //   K1b  bf16 8192*768  @ 0         (12.58 MB)
    //   V1b  bf16 8192*768  @ 12582912  (12.58 MB)
    //   hsb  bf16 8192*768  @ 25165824  (12.58 MB)
    //   Wb   bf16 1536*768  @ 37748736  ( 2.36 MB)
    //   bias fp32 1536      @ 40108032  ( 6 KB)
    char* ws = (char*)d_ws;
    unsigned short* K1b   = (unsigned short*)(ws);
    unsigned short* V1b   = (unsigned short*)(ws + 12582912);
    unsigned short* hsb   = (unsigned short*)(ws + 25165824);
    unsigned short* Wb    = (unsigned short*)(ws + 37748736);
    float*          biasp = (float*)(ws + 40108032);

    cast_pack<<<(NHS4 + NW4) / 256, 256, 0, stream>>>(hs, Kw, Vw, Kb, Vb, hsb, Wb, biasp);

    dim3 g1(NTOT / TBN, MTOT / TBM);   // 12 x 64 = 768 blocks, 3 blocks/CU
    gemm_mfma<<<g1, 256, 0, stream>>>(hsb, Wb, biasp, K1b, V1b);

    scan_gather<<<BSZ * NH * 4, LQ, 0, stream>>>(K1b, V1b, rh, bw, out);
}